// Round 2
// baseline (1086.373 us; speedup 1.0000x reference)
//
#include <hip/hip_runtime.h>
#include <hip/hip_bf16.h>

typedef unsigned short u16;
using bf16x8 = __attribute__((ext_vector_type(8))) short;
using f32x4  = __attribute__((ext_vector_type(4))) float;

#define EPSF 2.220446049250313e-16f
#define NS 4096      // samples
#define KC 6272      // 128 ch * 49 patch

__device__ __forceinline__ u16 f2bf(float f){
  union { float f; unsigned u; } x; x.f = f;
  unsigned r = (x.u + 0x7FFFu + ((x.u >> 16) & 1u)) >> 16;   // RNE
  return (u16)r;
}

#define GPTR(p) ((const __attribute__((address_space(1))) void*)(p))
#define LPTR(p) ((__attribute__((address_space(3))) void*)(p))

// ---------------- indices from fields ----------------
// idx layout: [ix_t | iy_t | ix_r | iy_r], 4096 each
__global__ void k_idx(const float* __restrict__ tfld, const float* __restrict__ rfld,
                      int* __restrict__ idx){
  int t = blockIdx.x * 256 + threadIdx.x;
  if (t >= 2 * NS) return;
  const float* f = (t < NS) ? tfld : rfld;
  int s = t & (NS - 1);
  int base = (t < NS) ? 0 : 2 * NS;
  float gx = (f[2*s]   + 1.0f) * 0.5f * 83.0f;   // (u+1)*0.5*(W-1), W=84
  float gy = (f[2*s+1] + 1.0f) * 0.5f * 83.0f;
  idx[base + s]      = (int)fminf(fmaxf(rintf(gx), 0.0f), 83.0f);
  idx[base + NS + s] = (int)fminf(fmaxf(rintf(gy), 0.0f), 83.0f);
}

// ---------------- per-channel mean of refer gather ----------------
__global__ __launch_bounds__(64) void k_mean(const float* __restrict__ refer,
                                             const int* __restrict__ idx,
                                             float* __restrict__ ymean){
  int co = blockIdx.x;                 // 0..6271
  int c = co / 49, p = co % 49;
  int ki = p / 7, kj = p % 7;
  const float* plane = refer + ((size_t)c << 16);
  const int* ixr = idx + 2 * NS;
  const int* iyr = idx + 3 * NS;
  float sum = 0.f;
  for (int s = threadIdx.x; s < NS; s += 64){
    int x = ixr[s] * 3 + kj;
    int y = iyr[s] * 3 + ki;
    sum += plane[y * 256 + x];
  }
  #pragma unroll
  for (int o = 32; o > 0; o >>= 1) sum += __shfl_down(sum, o);
  if (threadIdx.x == 0) ymean[co] = sum * (1.0f / 4096.0f);
}

// ---------------- gather + center + per-sample sum-of-squares ----------------
// X layout: (4096 samples, 6272 k) row-major bf16, k = c*49 + ki*7 + kj
__global__ __launch_bounds__(256) void k_gather(const float* __restrict__ feat,
                                                const int* __restrict__ ixv,
                                                const int* __restrict__ iyv,
                                                const float* __restrict__ ymean,
                                                u16* __restrict__ X,
                                                float* __restrict__ nsq){
  int c = blockIdx.x;                          // 0..127
  int s = blockIdx.y * 256 + threadIdx.x;      // 0..4095
  const float* plane = feat + ((size_t)c << 16);
  int bx = ixv[s] * 3, by = iyv[s] * 3;
  const float* mrow = ymean + c * 49;
  u16* xrow = X + (size_t)s * KC + c * 49;
  float ss = 0.f;
  #pragma unroll
  for (int ki = 0; ki < 7; ++ki){
    #pragma unroll
    for (int kj = 0; kj < 7; ++kj){
      float v  = plane[(by + ki) * 256 + (bx + kj)];
      float xc = v - mrow[ki * 7 + kj];
      ss += xc * xc;
      xrow[ki * 7 + kj] = f2bf(xc);
    }
  }
  atomicAdd(&nsq[s], ss);
}

// ---------------- reciprocal norms ----------------
__global__ void k_rnorm(const float* __restrict__ nsq, float* __restrict__ rn){
  int i = blockIdx.x * 256 + threadIdx.x;
  if (i < 2 * NS) rn[i] = 1.0f / (sqrtf(nsq[i]) + EPSF);
}

// ---------------- mask patch gather (k-major, fp32) + squared norms ----------------
__global__ void k_maskg(const float* __restrict__ mask,
                        const int* __restrict__ ixv, const int* __restrict__ iyv,
                        float* __restrict__ P, float* __restrict__ nsq){
  int s = blockIdx.x * 256 + threadIdx.x;
  if (s >= NS) return;
  int bx = ixv[s] * 3, by = iyv[s] * 3;
  float ss = 0.f;
  #pragma unroll
  for (int ki = 0; ki < 7; ++ki){
    #pragma unroll
    for (int kj = 0; kj < 7; ++kj){
      float v = mask[(by + ki) * 256 + (bx + kj)];
      P[(ki * 7 + kj) * NS + s] = v;
      ss += v * v;
    }
  }
  nsq[s] = ss;
}

// ---------------- d_prog: D[i][j] = (10/49)*max(0, nrp[j]+ntp[i]-2*tp_j.rp_i) ----------------
__global__ __launch_bounds__(256) void k_dprog(const float* __restrict__ TP,
                                               const float* __restrict__ RP,
                                               const float* __restrict__ ntp,
                                               const float* __restrict__ nrp,
                                               float* __restrict__ D){
  __shared__ float Ts[49][128];   // tp slice over j
  __shared__ float Rs[49][128];   // rp slice over i
  int j0 = blockIdx.x * 128, i0 = blockIdx.y * 128;
  for (int e = threadIdx.x; e < 49 * 128; e += 256){
    int k = e >> 7, s = e & 127;
    Ts[k][s] = TP[k * NS + j0 + s];
    Rs[k][s] = RP[k * NS + i0 + s];
  }
  __syncthreads();
  int tx = threadIdx.x & 15, ty = threadIdx.x >> 4;
  float acc[8][8] = {};
  for (int k = 0; k < 49; ++k){
    float ra[8], rb[8];
    #pragma unroll
    for (int a = 0; a < 8; ++a) ra[a] = Rs[k][ty * 8 + a];
    #pragma unroll
    for (int b = 0; b < 8; ++b) rb[b] = Ts[k][tx * 8 + b];
    #pragma unroll
    for (int a = 0; a < 8; ++a)
      #pragma unroll
      for (int b = 0; b < 8; ++b) acc[a][b] += ra[a] * rb[b];
  }
  #pragma unroll
  for (int a = 0; a < 8; ++a){
    int i = i0 + ty * 8 + a;
    float ni = ntp[i];
    #pragma unroll
    for (int b = 0; b < 8; ++b){
      int j = j0 + tx * 8 + b;
      float v = nrp[j] + ni - 2.0f * acc[a][b];
      D[(size_t)i * NS + j] = fmaxf(v, 0.0f) * (10.0f / 49.0f);
    }
  }
}

// ---------------- main GEMM: sim = Xt . Xr^T over K=6272, epilogue adds cos-dist ----------------
// m97-style: 128x128 tile, BK=64, global_load_lds(16B) with XOR chunk swizzle,
// 4 waves each computing 4x4 grid of 16x16x32 bf16 MFMAs.
__global__ __launch_bounds__(256) void k_gemm(const u16* __restrict__ Xt,
                                              const u16* __restrict__ Xr,
                                              const float* __restrict__ rnt,
                                              const float* __restrict__ rnr,
                                              float* __restrict__ D){
  __shared__ u16 As[128 * 64];
  __shared__ u16 Bs[128 * 64];
  const int tid  = threadIdx.x;
  const int lane = tid & 63;
  const int w    = tid >> 6;
  const int wm   = w >> 1, wn = w & 1;
  const int i0 = blockIdx.y * 128, j0 = blockIdx.x * 128;

  // staging: wave w stages rows [w*32, w*32+32) of both tiles, 4 issues of 8 rows.
  // lds slot (row r, chunk-slot cs) holds global chunk (cs ^ (r&7)) -> conflict-free frag reads
  const int srow = lane >> 3;
  const int cs   = lane & 7;
  const u16* ga[4]; const u16* gb[4];
  u16* la[4]; u16* lb[4];
  #pragma unroll
  for (int ii = 0; ii < 4; ++ii){
    int rb = w * 32 + ii * 8 + srow;
    int ch = cs ^ (rb & 7);
    ga[ii] = Xt + (size_t)(i0 + rb) * KC + ch * 8;
    gb[ii] = Xr + (size_t)(j0 + rb) * KC + ch * 8;
    la[ii] = As + (w * 32 + ii * 8) * 64;
    lb[ii] = Bs + (w * 32 + ii * 8) * 64;
  }

  const int quad = lane >> 4;
  const int mrow = lane & 15;
  int offA[2][4], offB[2][4];
  #pragma unroll
  for (int kk = 0; kk < 2; ++kk){
    #pragma unroll
    for (int t = 0; t < 4; ++t){
      int rA = wm * 64 + t * 16 + mrow;
      offA[kk][t] = rA * 64 + (((kk * 4 + quad) ^ (rA & 7)) * 8);
      int rB = wn * 64 + t * 16 + mrow;
      offB[kk][t] = rB * 64 + (((kk * 4 + quad) ^ (rB & 7)) * 8);
    }
  }

  f32x4 acc[4][4] = {};

  for (int kt = 0; kt < 98; ++kt){        // 98 * 64 = 6272
    #pragma unroll
    for (int ii = 0; ii < 4; ++ii){
      __builtin_amdgcn_global_load_lds(GPTR(ga[ii]), LPTR(la[ii]), 16, 0, 0);
      __builtin_amdgcn_global_load_lds(GPTR(gb[ii]), LPTR(lb[ii]), 16, 0, 0);
      ga[ii] += 64; gb[ii] += 64;
    }
    __syncthreads();
    #pragma unroll
    for (int kk = 0; kk < 2; ++kk){
      bf16x8 af[4], bfr[4];
      #pragma unroll
      for (int t = 0; t < 4; ++t){
        af[t]  = *(const bf16x8*)(As + offA[kk][t]);
        bfr[t] = *(const bf16x8*)(Bs + offB[kk][t]);
      }
      #pragma unroll
      for (int a = 0; a < 4; ++a)
        #pragma unroll
        for (int b = 0; b < 4; ++b)
          acc[a][b] = __builtin_amdgcn_mfma_f32_16x16x32_bf16(af[a], bfr[b], acc[a][b], 0, 0, 0);
    }
    __syncthreads();
  }

  // epilogue: C/D layout col=lane&15 (j), row=quad*4+reg (i)
  #pragma unroll
  for (int b = 0; b < 4; ++b){
    int j = j0 + wn * 64 + b * 16 + mrow;
    float rj = rnr[j];
    #pragma unroll
    for (int a = 0; a < 4; ++a){
      #pragma unroll
      for (int r = 0; r < 4; ++r){
        int i = i0 + wm * 64 + a * 16 + quad * 4 + r;
        float sim  = acc[a][b][r] * rnt[i] * rj;
        float dcos = fmaxf((1.0f - sim) * 0.5f, 0.0f);
        D[(size_t)i * NS + j] += dcos;
      }
    }
  }
}

// ---------------- per-row: min -> w=exp(2(1-d/dmin)) -> log(maxw/sumw) ----------------
__global__ __launch_bounds__(256) void k_rowred(const float* __restrict__ D,
                                                float* __restrict__ logcx){
  int i = blockIdx.x, tid = threadIdx.x;
  const float* row = D + (size_t)i * NS;
  float v[16];
  float mn = 3.4e38f;
  #pragma unroll
  for (int t = 0; t < 16; ++t){ v[t] = row[tid + t * 256]; mn = fminf(mn, v[t]); }
  __shared__ float r1[256], r2[256];
  r1[tid] = mn; __syncthreads();
  for (int s2 = 128; s2 > 0; s2 >>= 1){
    if (tid < s2) r1[tid] = fminf(r1[tid], r1[tid + s2]);
    __syncthreads();
  }
  float inv = 1.0f / (r1[0] + EPSF);
  __syncthreads();
  float sw = 0.f, mw = 0.f;
  #pragma unroll
  for (int t = 0; t < 16; ++t){
    float wv = expf((1.0f - v[t] * inv) * 2.0f);
    sw += wv; mw = fmaxf(mw, wv);
  }
  r1[tid] = sw; r2[tid] = mw; __syncthreads();
  for (int s2 = 128; s2 > 0; s2 >>= 1){
    if (tid < s2){ r1[tid] += r1[tid + s2]; r2[tid] = fmaxf(r2[tid], r2[tid + s2]); }
    __syncthreads();
  }
  if (tid == 0) logcx[i] = logf(r2[0] / r1[0]);
}

__global__ void k_final(const float* __restrict__ logcx, float* __restrict__ out){
  int tid = threadIdx.x;
  float s = 0.f;
  for (int t = tid; t < NS; t += 256) s += logcx[t];
  __shared__ float r[256];
  r[tid] = s; __syncthreads();
  for (int k = 128; k > 0; k >>= 1){
    if (tid < k) r[tid] += r[tid + k];
    __syncthreads();
  }
  if (tid == 0) out[0] = -(r[0] * (1.0f / 4096.0f));
}

extern "C" void kernel_launch(void* const* d_in, const int* in_sizes, int n_in,
                              void* d_out, int out_size, void* d_ws, size_t ws_size,
                              hipStream_t stream){
  (void)in_sizes; (void)n_in; (void)out_size; (void)ws_size;
  const float* tfeat = (const float*)d_in[0];
  const float* rfeat = (const float*)d_in[1];
  const float* mask  = (const float*)d_in[2];
  const float* tfld  = (const float*)d_in[3];
  const float* rfld  = (const float*)d_in[4];

  char* p = (char*)d_ws;
  auto take = [&](size_t bytes) -> char* {
    char* r = p; p += (bytes + 255) & ~(size_t)255; return r;
  };
  int*   idx   = (int*)  take(4 * NS * sizeof(int));       // ix_t|iy_t|ix_r|iy_r
  float* ymean = (float*)take(KC * sizeof(float));
  float* nsq   = (float*)take(2 * NS * sizeof(float));     // [t|r]
  float* rn    = (float*)take(2 * NS * sizeof(float));     // [t|r]
  float* ntp   = (float*)take(NS * sizeof(float));
  float* nrp   = (float*)take(NS * sizeof(float));
  float* TP    = (float*)take((size_t)49 * NS * sizeof(float));
  float* RP    = (float*)take((size_t)49 * NS * sizeof(float));
  u16*   Xt    = (u16*)  take((size_t)NS * KC * sizeof(u16));
  u16*   Xr    = (u16*)  take((size_t)NS * KC * sizeof(u16));
  float* D     = (float*)take((size_t)NS * NS * sizeof(float));
  float* lcx   = (float*)take(NS * sizeof(float));

  hipMemsetAsync(nsq, 0, 2 * NS * sizeof(float), stream);
  k_idx<<<32, 256, 0, stream>>>(tfld, rfld, idx);
  k_mean<<<6272, 64, 0, stream>>>(rfeat, idx, ymean);
  k_gather<<<dim3(128, 16), 256, 0, stream>>>(tfeat, idx,          idx + NS,     ymean, Xt, nsq);
  k_gather<<<dim3(128, 16), 256, 0, stream>>>(rfeat, idx + 2 * NS, idx + 3 * NS, ymean, Xr, nsq + NS);
  k_rnorm<<<32, 256, 0, stream>>>(nsq, rn);
  k_maskg<<<16, 256, 0, stream>>>(mask, idx,          idx + NS,     TP, ntp);
  k_maskg<<<16, 256, 0, stream>>>(mask, idx + 2 * NS, idx + 3 * NS, RP, nrp);
  k_dprog<<<dim3(32, 32), 256, 0, stream>>>(TP, RP, ntp, nrp, D);
  k_gemm<<<dim3(32, 32), 256, 0, stream>>>(Xt, Xr, rn, rn + NS, D);
  k_rowred<<<4096, 256, 0, stream>>>(D, lcx);
  k_final<<<1, 256, 0, stream>>>(lcx, (float*)d_out);
}

// Round 3
// 729.206 us; speedup vs baseline: 1.4898x; 1.4898x over previous
//
#include <hip/hip_runtime.h>
#include <hip/hip_bf16.h>

typedef unsigned short u16;
using bf16x8 = __attribute__((ext_vector_type(8))) short;
using f32x4  = __attribute__((ext_vector_type(4))) float;

#define EPSF 2.220446049250313e-16f
#define NS 4096      // samples
#define KC 6272      // 128 ch * 49 patch

__device__ __forceinline__ u16 f2bf(float f){
  union { float f; unsigned u; } x; x.f = f;
  unsigned r = (x.u + 0x7FFFu + ((x.u >> 16) & 1u)) >> 16;   // RNE
  return (u16)r;
}

#define GPTR(p) ((const __attribute__((address_space(1))) void*)(p))
#define LPTR(p) ((__attribute__((address_space(3))) void*)(p))

// ---------------- indices from fields ----------------
// idx layout: [ix_t | iy_t | ix_r | iy_r], 4096 each
__global__ void k_idx(const float* __restrict__ tfld, const float* __restrict__ rfld,
                      int* __restrict__ idx){
  int t = blockIdx.x * 256 + threadIdx.x;
  if (t >= 2 * NS) return;
  const float* f = (t < NS) ? tfld : rfld;
  int s = t & (NS - 1);
  int base = (t < NS) ? 0 : 2 * NS;
  float gx = (f[2*s]   + 1.0f) * 0.5f * 83.0f;   // (u+1)*0.5*(W-1), W=84
  float gy = (f[2*s+1] + 1.0f) * 0.5f * 83.0f;
  idx[base + s]      = (int)fminf(fmaxf(rintf(gx), 0.0f), 83.0f);
  idx[base + NS + s] = (int)fminf(fmaxf(rintf(gy), 0.0f), 83.0f);
}

// ---------------- refer-position histogram ----------------
__global__ void k_hist(const int* __restrict__ ixr, const int* __restrict__ iyr,
                       int* __restrict__ H){
  int s = blockIdx.x * 256 + threadIdx.x;
  if (s < NS) atomicAdd(&H[iyr[s] * 84 + ixr[s]], 1);
}

// ---------------- per-channel mean via dense weighted correlation ----------------
// ymean[c,ki,kj] = (1/4096) * sum_pos H[y0,x0] * plane[y0*3+ki, x0*3+kj]
__global__ __launch_bounds__(256) void k_mean2(const float* __restrict__ refer,
                                               const int* __restrict__ H,
                                               float* __restrict__ ymean){
  __shared__ int   Hs[7056];
  __shared__ float part[4][49];
  int c = blockIdx.x;
  const float* plane = refer + ((size_t)c << 16);
  for (int p = threadIdx.x; p < 7056; p += 256) Hs[p] = H[p];
  __syncthreads();
  float acc[49];
  #pragma unroll
  for (int k = 0; k < 49; ++k) acc[k] = 0.f;
  int y0 = 0, x0 = threadIdx.x;
  while (x0 >= 84){ x0 -= 84; ++y0; }
  for (; y0 < 84; ){
    int w = Hs[y0 * 84 + x0];
    if (w){
      float fw = (float)w;
      const float* pp = plane + (y0 * 3) * 256 + x0 * 3;
      #pragma unroll
      for (int ki = 0; ki < 7; ++ki)
        #pragma unroll
        for (int kj = 0; kj < 7; ++kj)
          acc[ki * 7 + kj] += fw * pp[ki * 256 + kj];
    }
    y0 += 3; x0 += 4;                      // advance by 256 = 3*84 + 4
    if (x0 >= 84){ x0 -= 84; ++y0; }
  }
  int lane = threadIdx.x & 63, wid = threadIdx.x >> 6;
  #pragma unroll
  for (int k = 0; k < 49; ++k){
    float v = acc[k];
    #pragma unroll
    for (int o = 32; o > 0; o >>= 1) v += __shfl_down(v, o);
    if (lane == 0) part[wid][k] = v;
  }
  __syncthreads();
  for (int k = threadIdx.x; k < 49; k += 256)
    ymean[c * 49 + k] = (part[0][k] + part[1][k] + part[2][k] + part[3][k]) * (1.0f / 4096.0f);
}

// ---------------- gather + center + per-sample sum-of-squares ----------------
// X layout: (4096 samples, 6272 k) row-major bf16, k = c*49 + ki*7 + kj
__global__ __launch_bounds__(256) void k_gather(const float* __restrict__ feat,
                                                const int* __restrict__ ixv,
                                                const int* __restrict__ iyv,
                                                const float* __restrict__ ymean,
                                                u16* __restrict__ X,
                                                float* __restrict__ nsq){
  int c = blockIdx.x;                          // 0..127
  int s = blockIdx.y * 256 + threadIdx.x;      // 0..4095
  const float* plane = feat + ((size_t)c << 16);
  int bx = ixv[s] * 3, by = iyv[s] * 3;
  const float* mrow = ymean + c * 49;
  u16* xrow = X + (size_t)s * KC + c * 49;
  float ss = 0.f;
  #pragma unroll
  for (int ki = 0; ki < 7; ++ki){
    #pragma unroll
    for (int kj = 0; kj < 7; ++kj){
      float v  = plane[(by + ki) * 256 + (bx + kj)];
      float xc = v - mrow[ki * 7 + kj];
      ss += xc * xc;
      xrow[ki * 7 + kj] = f2bf(xc);
    }
  }
  atomicAdd(&nsq[s], ss);
}

// ---------------- reciprocal norms ----------------
__global__ void k_rnorm(const float* __restrict__ nsq, float* __restrict__ rn){
  int i = blockIdx.x * 256 + threadIdx.x;
  if (i < 2 * NS) rn[i] = 1.0f / (sqrtf(nsq[i]) + EPSF);
}

// ---------------- mask patch gather (k-major, fp32) + squared norms ----------------
__global__ void k_maskg(const float* __restrict__ mask,
                        const int* __restrict__ ixv, const int* __restrict__ iyv,
                        float* __restrict__ P, float* __restrict__ nsq){
  int s = blockIdx.x * 256 + threadIdx.x;
  if (s >= NS) return;
  int bx = ixv[s] * 3, by = iyv[s] * 3;
  float ss = 0.f;
  #pragma unroll
  for (int ki = 0; ki < 7; ++ki){
    #pragma unroll
    for (int kj = 0; kj < 7; ++kj){
      float v = mask[(by + ki) * 256 + (bx + kj)];
      P[(ki * 7 + kj) * NS + s] = v;
      ss += v * v;
    }
  }
  nsq[s] = ss;
}

// ---------------- d_prog: D[i][j] = (10/49)*max(0, nrp[j]+ntp[i]-2*tp_j.rp_i) ----------------
__global__ __launch_bounds__(256) void k_dprog(const float* __restrict__ TP,
                                               const float* __restrict__ RP,
                                               const float* __restrict__ ntp,
                                               const float* __restrict__ nrp,
                                               float* __restrict__ D){
  __shared__ float Ts[49][128];   // tp slice over j
  __shared__ float Rs[49][128];   // rp slice over i
  int j0 = blockIdx.x * 128, i0 = blockIdx.y * 128;
  for (int e = threadIdx.x; e < 49 * 128; e += 256){
    int k = e >> 7, s = e & 127;
    Ts[k][s] = TP[k * NS + j0 + s];
    Rs[k][s] = RP[k * NS + i0 + s];
  }
  __syncthreads();
  int tx = threadIdx.x & 15, ty = threadIdx.x >> 4;
  float acc[8][8] = {};
  for (int k = 0; k < 49; ++k){
    float ra[8], rb[8];
    #pragma unroll
    for (int a = 0; a < 8; ++a) ra[a] = Rs[k][ty * 8 + a];
    #pragma unroll
    for (int b = 0; b < 8; ++b) rb[b] = Ts[k][tx * 8 + b];
    #pragma unroll
    for (int a = 0; a < 8; ++a)
      #pragma unroll
      for (int b = 0; b < 8; ++b) acc[a][b] += ra[a] * rb[b];
  }
  #pragma unroll
  for (int a = 0; a < 8; ++a){
    int i = i0 + ty * 8 + a;
    float ni = ntp[i];
    #pragma unroll
    for (int b = 0; b < 8; ++b){
      int j = j0 + tx * 8 + b;
      float v = nrp[j] + ni - 2.0f * acc[a][b];
      D[(size_t)i * NS + j] = fmaxf(v, 0.0f) * (10.0f / 49.0f);
    }
  }
}

// ---------------- main GEMM: sim = Xt . Xr^T over K=6272, epilogue adds cos-dist ----------------
// m97-style: 128x128 tile, BK=64, global_load_lds(16B) with XOR chunk swizzle.
// Register-trimmed: exploit ch = cs^srow invariance (one global ptr per matrix,
// issue offsets ii*8*KC) and mrow&7 LDS-offset invariance (t-offset folds into
// ds_read immediate) to target <=128 arch VGPRs -> 4 blocks/CU, no dispatch tail.
__global__ __launch_bounds__(256) void k_gemm(const u16* __restrict__ Xt,
                                              const u16* __restrict__ Xr,
                                              const float* __restrict__ rnt,
                                              const float* __restrict__ rnr,
                                              float* __restrict__ D){
  __shared__ u16 As[128 * 64];
  __shared__ u16 Bs[128 * 64];
  const int tid  = threadIdx.x;
  const int lane = tid & 63;
  const int w    = tid >> 6;
  const int wm   = w >> 1, wn = w & 1;
  const int i0 = blockIdx.y * 128, j0 = blockIdx.x * 128;

  // staging: wave w stages rows [w*32, w*32+32), 4 issues of 8 rows each.
  // lds slot (row r, chunk-slot cs) holds global chunk (cs ^ (r&7)).
  const int srow = lane >> 3;          // 0..7
  const int cs   = lane & 7;
  const int ch   = cs ^ srow;          // issue-invariant: (row+8k)&7 == srow
  const u16* ga = Xt + (size_t)(i0 + w * 32 + srow) * KC + ch * 8;
  const u16* gb = Xr + (size_t)(j0 + w * 32 + srow) * KC + ch * 8;
  u16* la = As + (w * 32) * 64;        // wave-uniform LDS base
  u16* lb = Bs + (w * 32) * 64;

  const int quad = lane >> 4;
  const int mrow = lane & 15;
  const int m7   = mrow & 7;
  // LDS frag indices (u16 units); t-offset = t*1024 folds into ds_read imm
  const int ia0 = (wm * 64 + mrow) * 64 + ((quad    ^ m7) * 8);
  const int ia1 = (wm * 64 + mrow) * 64 + (((4+quad)^ m7) * 8);
  const int ib0 = (wn * 64 + mrow) * 64 + ((quad    ^ m7) * 8);
  const int ib1 = (wn * 64 + mrow) * 64 + (((4+quad)^ m7) * 8);

  f32x4 acc[4][4] = {};

  for (int kt = 0; kt < 98; ++kt){        // 98 * 64 = 6272
    #pragma unroll
    for (int ii = 0; ii < 4; ++ii){
      __builtin_amdgcn_global_load_lds(GPTR(ga + ii * 8 * KC), LPTR(la + ii * 8 * 64), 16, 0, 0);
      __builtin_amdgcn_global_load_lds(GPTR(gb + ii * 8 * KC), LPTR(lb + ii * 8 * 64), 16, 0, 0);
    }
    ga += 64; gb += 64;
    __syncthreads();
    {
      bf16x8 af[4], bfr[4];
      #pragma unroll
      for (int t = 0; t < 4; ++t){
        af[t]  = *(const bf16x8*)(As + ia0 + t * 1024);
        bfr[t] = *(const bf16x8*)(Bs + ib0 + t * 1024);
      }
      #pragma unroll
      for (int a = 0; a < 4; ++a)
        #pragma unroll
        for (int b = 0; b < 4; ++b)
          acc[a][b] = __builtin_amdgcn_mfma_f32_16x16x32_bf16(af[a], bfr[b], acc[a][b], 0, 0, 0);
      #pragma unroll
      for (int t = 0; t < 4; ++t){
        af[t]  = *(const bf16x8*)(As + ia1 + t * 1024);
        bfr[t] = *(const bf16x8*)(Bs + ib1 + t * 1024);
      }
      #pragma unroll
      for (int a = 0; a < 4; ++a)
        #pragma unroll
        for (int b = 0; b < 4; ++b)
          acc[a][b] = __builtin_amdgcn_mfma_f32_16x16x32_bf16(af[a], bfr[b], acc[a][b], 0, 0, 0);
    }
    __syncthreads();
  }

  // epilogue: C/D layout col=lane&15 (j), row=quad*4+reg (i)
  #pragma unroll
  for (int b = 0; b < 4; ++b){
    int j = j0 + wn * 64 + b * 16 + mrow;
    float rj = rnr[j];
    #pragma unroll
    for (int a = 0; a < 4; ++a){
      #pragma unroll
      for (int r = 0; r < 4; ++r){
        int i = i0 + wm * 64 + a * 16 + quad * 4 + r;
        float sim  = acc[a][b][r] * rnt[i] * rj;
        float dcos = fmaxf((1.0f - sim) * 0.5f, 0.0f);
        D[(size_t)i * NS + j] += dcos;
      }
    }
  }
}

// ---------------- per-row: min -> w=exp(2(1-d/dmin)) -> log(maxw/sumw) ----------------
__global__ __launch_bounds__(256) void k_rowred(const float* __restrict__ D,
                                                float* __restrict__ logcx){
  int i = blockIdx.x, tid = threadIdx.x;
  const float* row = D + (size_t)i * NS;
  float v[16];
  float mn = 3.4e38f;
  #pragma unroll
  for (int t = 0; t < 16; ++t){ v[t] = row[tid + t * 256]; mn = fminf(mn, v[t]); }
  __shared__ float r1[256], r2[256];
  r1[tid] = mn; __syncthreads();
  for (int s2 = 128; s2 > 0; s2 >>= 1){
    if (tid < s2) r1[tid] = fminf(r1[tid], r1[tid + s2]);
    __syncthreads();
  }
  float inv = 1.0f / (r1[0] + EPSF);
  __syncthreads();
  float sw = 0.f, mw = 0.f;
  #pragma unroll
  for (int t = 0; t < 16; ++t){
    float wv = expf((1.0f - v[t] * inv) * 2.0f);
    sw += wv; mw = fmaxf(mw, wv);
  }
  r1[tid] = sw; r2[tid] = mw; __syncthreads();
  for (int s2 = 128; s2 > 0; s2 >>= 1){
    if (tid < s2){ r1[tid] += r1[tid + s2]; r2[tid] = fmaxf(r2[tid], r2[tid + s2]); }
    __syncthreads();
  }
  if (tid == 0) logcx[i] = logf(r2[0] / r1[0]);
}

__global__ void k_final(const float* __restrict__ logcx, float* __restrict__ out){
  int tid = threadIdx.x;
  float s = 0.f;
  for (int t = tid; t < NS; t += 256) s += logcx[t];
  __shared__ float r[256];
  r[tid] = s; __syncthreads();
  for (int k = 128; k > 0; k >>= 1){
    if (tid < k) r[tid] += r[tid + k];
    __syncthreads();
  }
  if (tid == 0) out[0] = -(r[0] * (1.0f / 4096.0f));
}

extern "C" void kernel_launch(void* const* d_in, const int* in_sizes, int n_in,
                              void* d_out, int out_size, void* d_ws, size_t ws_size,
                              hipStream_t stream){
  (void)in_sizes; (void)n_in; (void)out_size; (void)ws_size;
  const float* tfeat = (const float*)d_in[0];
  const float* rfeat = (const float*)d_in[1];
  const float* mask  = (const float*)d_in[2];
  const float* tfld  = (const float*)d_in[3];
  const float* rfld  = (const float*)d_in[4];

  char* p = (char*)d_ws;
  auto take = [&](size_t bytes) -> char* {
    char* r = p; p += (bytes + 255) & ~(size_t)255; return r;
  };
  int*   idx   = (int*)  take(4 * NS * sizeof(int));       // ix_t|iy_t|ix_r|iy_r
  int*   H     = (int*)  take(7056 * sizeof(int));
  float* ymean = (float*)take(KC * sizeof(float));
  float* nsq   = (float*)take(2 * NS * sizeof(float));     // [t|r]
  float* rn    = (float*)take(2 * NS * sizeof(float));     // [t|r]
  float* ntp   = (float*)take(NS * sizeof(float));
  float* nrp   = (float*)take(NS * sizeof(float));
  float* TP    = (float*)take((size_t)49 * NS * sizeof(float));
  float* RP    = (float*)take((size_t)49 * NS * sizeof(float));
  u16*   Xt    = (u16*)  take((size_t)NS * KC * sizeof(u16));
  u16*   Xr    = (u16*)  take((size_t)NS * KC * sizeof(u16));
  float* D     = (float*)take((size_t)NS * NS * sizeof(float));
  float* lcx   = (float*)take(NS * sizeof(float));

  hipMemsetAsync(nsq, 0, 2 * NS * sizeof(float), stream);
  hipMemsetAsync(H, 0, 7056 * sizeof(int), stream);
  k_idx<<<32, 256, 0, stream>>>(tfld, rfld, idx);
  k_hist<<<16, 256, 0, stream>>>(idx + 2 * NS, idx + 3 * NS, H);
  k_mean2<<<128, 256, 0, stream>>>(rfeat, H, ymean);
  k_gather<<<dim3(128, 16), 256, 0, stream>>>(tfeat, idx,          idx + NS,     ymean, Xt, nsq);
  k_gather<<<dim3(128, 16), 256, 0, stream>>>(rfeat, idx + 2 * NS, idx + 3 * NS, ymean, Xr, nsq + NS);
  k_rnorm<<<32, 256, 0, stream>>>(nsq, rn);
  k_maskg<<<16, 256, 0, stream>>>(mask, idx,          idx + NS,     TP, ntp);
  k_maskg<<<16, 256, 0, stream>>>(mask, idx + 2 * NS, idx + 3 * NS, RP, nrp);
  k_dprog<<<dim3(32, 32), 256, 0, stream>>>(TP, RP, ntp, nrp, D);
  k_gemm<<<dim3(32, 32), 256, 0, stream>>>(Xt, Xr, rn, rn + NS, D);
  k_rowred<<<4096, 256, 0, stream>>>(D, lcx);
  k_final<<<1, 256, 0, stream>>>(lcx, (float*)d_out);
}

// Round 4
// 648.711 us; speedup vs baseline: 1.6747x; 1.1241x over previous
//
#include <hip/hip_runtime.h>
#include <hip/hip_bf16.h>

typedef unsigned short u16;
typedef unsigned char  u8;
typedef long long      i64;
using f32x4 = __attribute__((ext_vector_type(4))) float;

#define EPSF 2.220446049250313e-16f
#define NS 4096      // samples
#define KC 6272      // 128 ch * 49 patch (elements; also bytes in fp8)
#define FSCALE 32.0f

#define GPTR(p) ((const __attribute__((address_space(1))) void*)(p))
#define LPTR(p) ((__attribute__((address_space(3))) void*)(p))

__device__ __forceinline__ u8 f2fp8(float v){
  return (u8)(__builtin_amdgcn_cvt_pk_fp8_f32(v, v, 0, false) & 0xff);
}

// ---------------- indices + histogram + tile buckets ----------------
// idx layout: [ix_t | iy_t | ix_r | iy_r], 4096 each.
// buckets: position space 84x84 tiled 3x3 (28x28 tiles).
__global__ void k_idx(const float* __restrict__ tfld, const float* __restrict__ rfld,
                      int* __restrict__ idx, int* __restrict__ H,
                      int* __restrict__ cntT, int* __restrict__ bktT,
                      int* __restrict__ cntR, int* __restrict__ bktR){
  int t = blockIdx.x * 256 + threadIdx.x;
  if (t >= 2 * NS) return;
  const float* f = (t < NS) ? tfld : rfld;
  int s = t & (NS - 1);
  int base = (t < NS) ? 0 : 2 * NS;
  float gx = (f[2*s]   + 1.0f) * 0.5f * 83.0f;
  float gy = (f[2*s+1] + 1.0f) * 0.5f * 83.0f;
  int ix = (int)fminf(fmaxf(rintf(gx), 0.0f), 83.0f);
  int iy = (int)fminf(fmaxf(rintf(gy), 0.0f), 83.0f);
  idx[base + s]      = ix;
  idx[base + NS + s] = iy;
  int tile = (iy / 28) * 3 + (ix / 28);
  if (t < NS){
    int e = atomicAdd(&cntT[tile], 1);
    bktT[tile * 4096 + e] = s;
  } else {
    atomicAdd(&H[iy * 84 + ix], 1);
    int e = atomicAdd(&cntR[tile], 1);
    bktR[tile * 4096 + e] = s;
  }
}

// ---------------- per-channel mean via dense weighted correlation ----------------
__global__ __launch_bounds__(256) void k_mean2(const float* __restrict__ refer,
                                               const int* __restrict__ H,
                                               float* __restrict__ ymean){
  __shared__ int   Hs[7056];
  __shared__ float part[4][49];
  int c = blockIdx.x;
  const float* plane = refer + ((size_t)c << 16);
  for (int p = threadIdx.x; p < 7056; p += 256) Hs[p] = H[p];
  __syncthreads();
  float acc[49];
  #pragma unroll
  for (int k = 0; k < 49; ++k) acc[k] = 0.f;
  int y0 = 0, x0 = threadIdx.x;
  while (x0 >= 84){ x0 -= 84; ++y0; }
  for (; y0 < 84; ){
    int w = Hs[y0 * 84 + x0];
    if (w){
      float fw = (float)w;
      const float* pp = plane + (y0 * 3) * 256 + x0 * 3;
      #pragma unroll
      for (int ki = 0; ki < 7; ++ki)
        #pragma unroll
        for (int kj = 0; kj < 7; ++kj)
          acc[ki * 7 + kj] += fw * pp[ki * 256 + kj];
    }
    y0 += 3; x0 += 4;
    if (x0 >= 84){ x0 -= 84; ++y0; }
  }
  int lane = threadIdx.x & 63, wid = threadIdx.x >> 6;
  #pragma unroll
  for (int k = 0; k < 49; ++k){
    float v = acc[k];
    #pragma unroll
    for (int o = 32; o > 0; o >>= 1) v += __shfl_down(v, o);
    if (lane == 0) part[wid][k] = v;
  }
  __syncthreads();
  for (int k = threadIdx.x; k < 49; k += 256)
    ymean[c * 49 + k] = (part[0][k] + part[1][k] + part[2][k] + part[3][k]) * (1.0f / 4096.0f);
}

// ---------------- bucketed gather: LDS region + per-sample patch ----------------
// block = (channel, tile). Region = 88x88 floats from (ty*84, tx*84), stride 92 in LDS.
// Output X: (4096 samples, 6272 k) row-major fp8(e4m3, x*32), k = c*49 + ki*7 + kj
__global__ __launch_bounds__(256) void k_gather(const float* __restrict__ feat,
                                                const int* __restrict__ ixv,
                                                const int* __restrict__ iyv,
                                                const int* __restrict__ cnt,
                                                const int* __restrict__ bkt,
                                                const float* __restrict__ ymean,
                                                u8* __restrict__ X,
                                                float* __restrict__ nsq){
  __shared__ float R[88 * 92];
  __shared__ float ms[49];
  int c = blockIdx.x;      // 0..127
  int t = blockIdx.y;      // 0..8
  int ty = t / 3, tx = t % 3;
  const float* src = feat + ((size_t)c << 16) + (ty * 84) * 256 + tx * 84;
  for (int e = threadIdx.x; e < 88 * 22; e += 256){
    int r = e / 22, q = e % 22;
    *(f32x4*)&R[r * 92 + q * 4] = *(const f32x4*)(src + r * 256 + q * 4);
  }
  for (int k = threadIdx.x; k < 49; k += 256) ms[k] = ymean[c * 49 + k];
  __syncthreads();
  int n = cnt[t];
  const int* list = bkt + t * 4096;
  for (int e = threadIdx.x; e < n; e += 256){
    int s = list[e];
    int ly = iyv[s] * 3 - ty * 84;
    int lx = ixv[s] * 3 - tx * 84;
    u8* xrow = X + (size_t)s * KC + c * 49;
    float ss = 0.f;
    #pragma unroll
    for (int ki = 0; ki < 7; ++ki)
      #pragma unroll
      for (int kj = 0; kj < 7; ++kj){
        float xc = R[(ly + ki) * 92 + lx + kj] - ms[ki * 7 + kj];
        ss += xc * xc;
        xrow[ki * 7 + kj] = f2fp8(xc * FSCALE);
      }
    atomicAdd(&nsq[s], ss);
  }
}

// ---------------- reciprocal norms (1/FSCALE folded in) ----------------
__global__ void k_rnorm(const float* __restrict__ nsq, float* __restrict__ rn){
  int i = blockIdx.x * 256 + threadIdx.x;
  if (i < 2 * NS) rn[i] = (1.0f / FSCALE) / (sqrtf(nsq[i]) + EPSF);
}

// ---------------- mask patch gather (k-major, fp32) + squared norms ----------------
__global__ void k_maskg(const float* __restrict__ mask,
                        const int* __restrict__ ixv, const int* __restrict__ iyv,
                        float* __restrict__ P, float* __restrict__ nsq){
  int s = blockIdx.x * 256 + threadIdx.x;
  if (s >= NS) return;
  int bx = ixv[s] * 3, by = iyv[s] * 3;
  float ss = 0.f;
  #pragma unroll
  for (int ki = 0; ki < 7; ++ki){
    #pragma unroll
    for (int kj = 0; kj < 7; ++kj){
      float v = mask[(by + ki) * 256 + (bx + kj)];
      P[(ki * 7 + kj) * NS + s] = v;
      ss += v * v;
    }
  }
  nsq[s] = ss;
}

// ---------------- d_prog: D[i][j] = (10/49)*max(0, nrp[j]+ntp[i]-2*tp_j.rp_i) ----------------
__global__ __launch_bounds__(256) void k_dprog(const float* __restrict__ TP,
                                               const float* __restrict__ RP,
                                               const float* __restrict__ ntp,
                                               const float* __restrict__ nrp,
                                               float* __restrict__ D){
  __shared__ float Ts[49][128];
  __shared__ float Rs[49][128];
  int j0 = blockIdx.x * 128, i0 = blockIdx.y * 128;
  for (int e = threadIdx.x; e < 49 * 128; e += 256){
    int k = e >> 7, s = e & 127;
    Ts[k][s] = TP[k * NS + j0 + s];
    Rs[k][s] = RP[k * NS + i0 + s];
  }
  __syncthreads();
  int tx = threadIdx.x & 15, ty = threadIdx.x >> 4;
  float acc[8][8] = {};
  for (int k = 0; k < 49; ++k){
    float ra[8], rb[8];
    #pragma unroll
    for (int a = 0; a < 8; ++a) ra[a] = Rs[k][ty * 8 + a];
    #pragma unroll
    for (int b = 0; b < 8; ++b) rb[b] = Ts[k][tx * 8 + b];
    #pragma unroll
    for (int a = 0; a < 8; ++a)
      #pragma unroll
      for (int b = 0; b < 8; ++b) acc[a][b] += ra[a] * rb[b];
  }
  #pragma unroll
  for (int a = 0; a < 8; ++a){
    int i = i0 + ty * 8 + a;
    float ni = ntp[i];
    #pragma unroll
    for (int b = 0; b < 8; ++b){
      int j = j0 + tx * 8 + b;
      float v = nrp[j] + ni - 2.0f * acc[a][b];
      D[(size_t)i * NS + j] = fmaxf(v, 0.0f) * (10.0f / 49.0f);
    }
  }
}

// ---------------- main GEMM (fp8): sim = Xt . Xr^T over K=6272 ----------------
// 128x128 tile, BK=128 fp8 (128 B/row), 49 K-iters. global_load_lds 16B with
// 16B-chunk XOR swizzle (slot = chunk ^ (row&7)) -> conflict-managed ds_read_b64.
// XCD-region block swizzle: b&7 -> 8x16-tile region, b>>3 -> position in region,
// so each XCD's staging working set stays in its own L2.
__global__ __launch_bounds__(256) void k_gemm(const u8* __restrict__ Xt,
                                              const u8* __restrict__ Xr,
                                              const float* __restrict__ rnt,
                                              const float* __restrict__ rnr,
                                              float* __restrict__ D){
  __shared__ u8 As[128 * 128];
  __shared__ u8 Bs[128 * 128];
  const int tid  = threadIdx.x;
  const int lane = tid & 63;
  const int w    = tid >> 6;
  const int wm   = w >> 1, wn = w & 1;
  const int b    = blockIdx.x;
  const int xcd  = b & 7, kb = b >> 3;
  const int i0 = ((xcd & 3) * 8 + (kb & 7)) * 128;
  const int j0 = ((xcd >> 2) * 16 + (kb >> 3)) * 128;

  // staging: wave w stages rows [w*32, w*32+32), 4 issues of 8 rows each
  const int srow = lane >> 3;          // 0..7 (= row & 7)
  const int cs   = lane & 7;           // LDS 16B-slot
  const int ch   = cs ^ srow;          // global 16B-chunk
  const u8* ga = Xt + (size_t)(i0 + w * 32 + srow) * KC + ch * 16;
  const u8* gb = Xr + (size_t)(j0 + w * 32 + srow) * KC + ch * 16;
  u8* la = As + (w * 32) * 128;
  u8* lb = Bs + (w * 32) * 128;

  const int quad = lane >> 4;
  const int mrow = lane & 15;
  const int m7   = mrow & 7;
  const int qh   = quad >> 1;
  const int rba  = (wm * 64 + mrow) * 128 + (quad & 1) * 8;   // + slot*16 + t*2048
  const int rbb  = (wn * 64 + mrow) * 128 + (quad & 1) * 8;

  f32x4 acc[4][4] = {};

  for (int kt = 0; kt < 49; ++kt){        // 49 * 128 = 6272
    #pragma unroll
    for (int ii = 0; ii < 4; ++ii){
      __builtin_amdgcn_global_load_lds(GPTR(ga + ii * 8 * KC), LPTR(la + ii * 8 * 128), 16, 0, 0);
      __builtin_amdgcn_global_load_lds(GPTR(gb + ii * 8 * KC), LPTR(lb + ii * 8 * 128), 16, 0, 0);
    }
    ga += 128; gb += 128;
    __syncthreads();
    #pragma unroll
    for (int kk = 0; kk < 4; ++kk){
      const int slot = ((kk * 2 + qh) ^ m7) * 16;
      i64 af[4], bfr[4];
      #pragma unroll
      for (int t = 0; t < 4; ++t){
        af[t]  = *(const i64*)(As + rba + t * 2048 + slot);
        bfr[t] = *(const i64*)(Bs + rbb + t * 2048 + slot);
      }
      #pragma unroll
      for (int a = 0; a < 4; ++a)
        #pragma unroll
        for (int bq = 0; bq < 4; ++bq)
          acc[a][bq] = __builtin_amdgcn_mfma_f32_16x16x32_fp8_fp8(af[a], bfr[bq], acc[a][bq], 0, 0, 0);
    }
    __syncthreads();
  }

  // epilogue: C/D layout col=lane&15 (j), row=quad*4+reg (i); rn carries 1/FSCALE
  #pragma unroll
  for (int bq = 0; bq < 4; ++bq){
    int j = j0 + wn * 64 + bq * 16 + mrow;
    float rj = rnr[j];
    #pragma unroll
    for (int a = 0; a < 4; ++a){
      #pragma unroll
      for (int r = 0; r < 4; ++r){
        int i = i0 + wm * 64 + a * 16 + quad * 4 + r;
        float sim  = acc[a][bq][r] * rnt[i] * rj;
        float dcos = fmaxf((1.0f - sim) * 0.5f, 0.0f);
        D[(size_t)i * NS + j] += dcos;
      }
    }
  }
}

// ---------------- per-row: min -> w=exp(2(1-d/dmin)) -> log(maxw/sumw) ----------------
__global__ __launch_bounds__(256) void k_rowred(const float* __restrict__ D,
                                                float* __restrict__ logcx){
  int i = blockIdx.x, tid = threadIdx.x;
  const float* row = D + (size_t)i * NS;
  float v[16];
  float mn = 3.4e38f;
  #pragma unroll
  for (int t = 0; t < 16; ++t){ v[t] = row[tid + t * 256]; mn = fminf(mn, v[t]); }
  __shared__ float r1[256], r2[256];
  r1[tid] = mn; __syncthreads();
  for (int s2 = 128; s2 > 0; s2 >>= 1){
    if (tid < s2) r1[tid] = fminf(r1[tid], r1[tid + s2]);
    __syncthreads();
  }
  float inv = 1.0f / (r1[0] + EPSF);
  __syncthreads();
  float sw = 0.f, mw = 0.f;
  #pragma unroll
  for (int t = 0; t < 16; ++t){
    float wv = expf((1.0f - v[t] * inv) * 2.0f);
    sw += wv; mw = fmaxf(mw, wv);
  }
  r1[tid] = sw; r2[tid] = mw; __syncthreads();
  for (int s2 = 128; s2 > 0; s2 >>= 1){
    if (tid < s2){ r1[tid] += r1[tid + s2]; r2[tid] = fmaxf(r2[tid], r2[tid + s2]); }
    __syncthreads();
  }
  if (tid == 0) logcx[i] = logf(r2[0] / r1[0]);
}

__global__ void k_final(const float* __restrict__ logcx, float* __restrict__ out){
  int tid = threadIdx.x;
  float s = 0.f;
  for (int t = tid; t < NS; t += 256) s += logcx[t];
  __shared__ float r[256];
  r[tid] = s; __syncthreads();
  for (int k = 128; k > 0; k >>= 1){
    if (tid < k) r[tid] += r[tid + k];
    __syncthreads();
  }
  if (tid == 0) out[0] = -(r[0] * (1.0f / 4096.0f));
}

extern "C" void kernel_launch(void* const* d_in, const int* in_sizes, int n_in,
                              void* d_out, int out_size, void* d_ws, size_t ws_size,
                              hipStream_t stream){
  (void)in_sizes; (void)n_in; (void)out_size; (void)ws_size;
  const float* tfeat = (const float*)d_in[0];
  const float* rfeat = (const float*)d_in[1];
  const float* mask  = (const float*)d_in[2];
  const float* tfld  = (const float*)d_in[3];
  const float* rfld  = (const float*)d_in[4];

  char* p = (char*)d_ws;
  auto take = [&](size_t bytes) -> char* {
    char* r = p; p += (bytes + 255) & ~(size_t)255; return r;
  };
  int*   idx   = (int*)  take(4 * NS * sizeof(int));
  int*   H     = (int*)  take(7056 * sizeof(int));
  int*   cntT  = (int*)  take(9 * sizeof(int));
  int*   cntR  = (int*)  take(9 * sizeof(int));
  int*   bktT  = (int*)  take(9 * 4096 * sizeof(int));
  int*   bktR  = (int*)  take(9 * 4096 * sizeof(int));
  float* ymean = (float*)take(KC * sizeof(float));
  float* nsq   = (float*)take(2 * NS * sizeof(float));
  float* rn    = (float*)take(2 * NS * sizeof(float));
  float* ntp   = (float*)take(NS * sizeof(float));
  float* nrp   = (float*)take(NS * sizeof(float));
  float* TP    = (float*)take((size_t)49 * NS * sizeof(float));
  float* RP    = (float*)take((size_t)49 * NS * sizeof(float));
  u8*    Xt    = (u8*)   take((size_t)NS * KC);
  u8*    Xr    = (u8*)   take((size_t)NS * KC);
  float* D     = (float*)take((size_t)NS * NS * sizeof(float));
  float* lcx   = (float*)take(NS * sizeof(float));

  hipMemsetAsync(nsq, 0, 2 * NS * sizeof(float), stream);
  hipMemsetAsync(H, 0, 7056 * sizeof(int), stream);
  hipMemsetAsync(cntT, 0, 9 * sizeof(int), stream);
  hipMemsetAsync(cntR, 0, 9 * sizeof(int), stream);
  k_idx<<<32, 256, 0, stream>>>(tfld, rfld, idx, H, cntT, bktT, cntR, bktR);
  k_mean2<<<128, 256, 0, stream>>>(rfeat, H, ymean);
  k_gather<<<dim3(128, 9), 256, 0, stream>>>(tfeat, idx,          idx + NS,     cntT, bktT, ymean, Xt, nsq);
  k_gather<<<dim3(128, 9), 256, 0, stream>>>(rfeat, idx + 2 * NS, idx + 3 * NS, cntR, bktR, ymean, Xr, nsq + NS);
  k_rnorm<<<32, 256, 0, stream>>>(nsq, rn);
  k_maskg<<<16, 256, 0, stream>>>(mask, idx,          idx + NS,     TP, ntp);
  k_maskg<<<16, 256, 0, stream>>>(mask, idx + 2 * NS, idx + 3 * NS, RP, nrp);
  k_dprog<<<dim3(32, 32), 256, 0, stream>>>(TP, RP, ntp, nrp, D);
  k_gemm<<<1024, 256, 0, stream>>>(Xt, Xr, rn, rn + NS, D);
  k_rowred<<<4096, 256, 0, stream>>>(D, lcx);
  k_final<<<1, 256, 0, stream>>>(lcx, (float*)d_out);
}